// Round 14
// baseline (23.493 us; speedup 1.0000x reference)
//
#include <hip/hip_runtime.h>
#include <math.h>

#define L_OBS   512
#define NSEG    8192
#define NB      8
#define EPS_PAR 1e-4f
#define ANG_STEP 0.012271846644580566f  // 2*pi / 512

// rotation by 17*ANG_STEP (arc width for 16 beams + 1-step margin each side)
#define C17   0.97831738f
#define S17   0.20711137f

#define NCHK   8
#define CHKSZ  1024                     // segs per chunk (= blockDim)

// Single dispatch. Block = (b, 16-beam group): 256 blocks x 1024 threads
// (1 block/CU, 16 waves). Per chunk of 1024 segs: every thread culls ONE seg
// via cross-product cone-overlap (R12-proven, bit-exact), wave-aggregated
// compaction (__ballot + 1 LDS atomic per wave), double-buffered LDS so
// stage(c+1) overlaps inner(c) with ONE barrier per chunk. Thread =
// (bm = t&15, slice = t>>4) strides compacted list by 64. Capacity == chunk
// -> overflow impossible -> superset of hittable set -> exact min. Outputs
// written inline: no workspace, no finalize dispatch. fmin over a permuted
// set is order-independent -> deterministic.
__global__ __launch_bounds__(1024) void raycast14_kernel(
    const float4* __restrict__ seg, const float* __restrict__ pose,
    float* __restrict__ out) {
    __shared__ float4 s4[2][CHKSZ];   // 32 KB, double-buffered {sx,sy,xd,yd}
    __shared__ float  red[16][16];    // [wave][beam]
    __shared__ int    s_cnt[NCHK];

    const int blk = blockIdx.x;       // 256 = 8b * 32grp
    const int b   = blk >> 5;
    const int grp = blk & 31;
    const int t   = threadIdx.x;
    const int lane  = t & 63;
    const int wv    = t >> 6;         // 0..15
    const int bm    = t & 15;
    const int slice = t >> 4;         // 0..63

    const float x1 = pose[b * 3 + 0];
    const float y1 = pose[b * 3 + 1];
    const float th = pose[b * 3 + 2];
    const int   B0 = grp << 4;

    // Arc bounds [d0, d1]: beams B0-1 .. B0+16 (margin 1 step each side).
    const float aa = (float)(B0 - 1) * ANG_STEP + th;
    const float d0x = cosf(aa), d0y = sinf(aa);
    const float d1x = d0x * C17 - d0y * S17;
    const float d1y = d0x * S17 + d0y * C17;

    // This thread's beam direction.
    const float ang = (float)(B0 + bm) * ANG_STEP + th;
    const float rx = cosf(ang), ry = sinf(ang);
    const float INF = __builtin_inff();

    if (t < NCHK) s_cnt[t] = 0;
    __syncthreads();

    // stage+cull one chunk (all 1024 threads, one seg each)
    auto stage = [&](int c) {
        float4 v = seg[(c << 10) + t];
        float ax = v.x - x1, ay = v.y - y1;     // P->A
        float bx = v.z - x1, by = v.w - y1;     // P->B
        float X0a = d0x * ay - d0y * ax;        // cross(d0, a)
        float Xa1 = ax * d1y - ay * d1x;        // cross(a, d1)
        float X0b = d0x * by - d0y * bx;        // cross(d0, b)
        float Xb1 = bx * d1y - by * d1x;        // cross(b, d1)
        float Xab = ax * by - ay * bx;          // cross(a, b)
        const float M = 0.25f;

        bool inA_a = (X0a >= -M) & (Xa1 >= -M);
        bool inA_b = (X0b >= -M) & (Xb1 >= -M);
        bool d0W, d1W;
        if (Xab >= 0.0f) {      // wedge CCW a -> b
            d0W = (X0a <=  M) & (X0b >= -M);
            d1W = (Xa1 >= -M) & (Xb1 <=  M);
        } else {                // wedge CCW b -> a
            d0W = (X0b <=  M) & (X0a >= -M);
            d1W = (Xb1 >= -M) & (Xa1 <=  M);
        }
        float la2 = ax * ax + ay * ay;
        float lb2 = bx * bx + by * by;
        bool degen = (Xab * Xab <= 4e-6f * la2 * lb2);  // P ~ on segment line
        bool keep = inA_a | inA_b | d0W | d1W | degen;

        // wave-aggregated compaction: 1 atomic per wave
        unsigned long long mk = __ballot(keep);
        int pos = __popcll(mk & ((1ULL << lane) - 1));
        int base = 0;
        if (lane == 0) base = atomicAdd(&s_cnt[c], (int)__popcll(mk));
        base = __shfl(base, 0);
        if (keep)
            s4[c & 1][base + pos] = make_float4(bx - ax, by - ay, -ax, -ay);
    };

    stage(0);
    __syncthreads();

    float umin = INF;
    for (int c = 0; c < NCHK; ++c) {
        if (c + 1 < NCHK) stage(c + 1);          // overlaps inner(c)

        const int n = s_cnt[c];
        const float4* __restrict__ p = s4[c & 1];
        for (int i = slice; i < n; i += 64) {
            float4 s = p[i];                  // {sx, sy, xd, yd}
            float rxs = s.y * rx - s.x * ry;
            float na  = s.x * s.w - s.y * s.z;
            float nb  = rx * s.w - ry * s.z;
            float r   = __builtin_amdgcn_rcpf(rxs);
            float ua  = na * r;
            float ub  = nb * r;
            bool ok = (fabsf(rxs) >= EPS_PAR) & (ub >= 0.0f) & (ub <= 1.0f) & (ua >= 0.0f);
            umin = fminf(umin, ok ? ua : INF);
        }
        __syncthreads();   // stage(c+1) done AND inner(c) readers done
    }

    // Reduce slices: within-wave (4 slices = lane bits 4,5), then 16 waves.
    umin = fminf(umin, __shfl_xor(umin, 16));
    umin = fminf(umin, __shfl_xor(umin, 32));
    if (lane < 16) red[wv][lane] = umin;
    __syncthreads();

    if (t < 16) {
        float m = red[0][t];
        #pragma unroll
        for (int j = 1; j < 16; ++j) m = fminf(m, red[j][t]);

        const int gbeam = B0 + t;
        const float angf = (float)gbeam * ANG_STEP + th;
        const float rxf = cosf(angf), ryf = sinf(angf);

        if (isinf(m)) {
            // No valid intersection: ref takes u_a[0] (argmin of all-inf -> idx 0).
            float4 s0 = seg[0];
            float sx = s0.z - s0.x, sy = s0.w - s0.y;
            float xd = x1 - s0.x,   yd = y1 - s0.y;
            float rxs   = sy * rxf - sx * ryf;
            float num_a = sx * yd - sy * xd;
            m = (fabsf(rxs) < EPS_PAR) ? 0.0f : (num_a / rxs);
        }

        float ix = x1 + rxf * m;
        float iy = y1 + ryf * m;
        float dx = ix - x1, dy = iy - y1;
        float c = cosf(th), s = sinf(th);
        const int gb = b * L_OBS + gbeam;
        out[gb * 2 + 0] = ix;
        out[gb * 2 + 1] = iy;
        const int off = NB * L_OBS * 2;
        out[off + gb * 2 + 0] =  dx * c + dy * s;   // R = [[c,-s],[s,c]], out = d @ R
        out[off + gb * 2 + 1] = -dx * s + dy * c;
    }
}

extern "C" void kernel_launch(void* const* d_in, const int* in_sizes, int n_in,
                              void* d_out, int out_size, void* d_ws, size_t ws_size,
                              hipStream_t stream) {
    const float4* seg  = (const float4*)d_in[0];   // (N,4) float32
    const float*  pose = (const float*)d_in[1];    // (B,3) float32
    float* out = (float*)d_out;

    raycast14_kernel<<<NB * 32, 1024, 0, stream>>>(seg, pose, out);
}

// Round 15
// 19.808 us; speedup vs baseline: 1.1860x; 1.1860x over previous
//
#include <hip/hip_runtime.h>
#include <math.h>

#define L_OBS   512
#define NSEG    8192
#define NB      8
#define EPS_PAR 1e-4f
#define ANG_STEP 0.012271846644580566f  // 2*pi / 512

// rotate by -1 beam step
#define C1    0.9999247f
#define S1    0.012271538f

#define SC2   16
#define CSEG2 (NSEG / SC2)               // 512 segs per block
#define PART_FLOATS (SC2 * NB * L_OBS)   // 256 KB

// R13 skeleton, consolidated: block = (b, beamgroup of 128 beams, segchunk of
// 512 segs), 512 threads (8 waves), grid 512 = 8b*4bg*16sc.
// All threads stage+cull one seg each (no idle half). Cull = R12/R13-proven
// cross-product cone-overlap; arc dirs derived from lane 0's beam dir via
// __shfl + exact rotations (d1 = +128 steps = pi/2 = (-y,x)), no extra sincos.
// LDS-compact (capacity == chunk -> no overflow; superset -> exact min).
// Wave w strides compacted list by 8; thread owns beams (B0+lane, +64).
__global__ __launch_bounds__(512) void raycast15_kernel(
    const float4* __restrict__ seg, const float* __restrict__ pose,
    float* __restrict__ part) {
    __shared__ float4 s4[CSEG2];     // compacted {sx, sy, xd, yd}
    __shared__ float  s_red[8][128];
    __shared__ int    s_n;

    const int gid = blockIdx.x;      // 512 = 8b * 4bg * 16sc
    const int sc = gid & (SC2 - 1);
    const int bg = (gid >> 4) & 3;
    const int b  = gid >> 6;

    const float x1 = pose[b * 3 + 0];
    const float y1 = pose[b * 3 + 1];
    const float th = pose[b * 3 + 2];

    const int t = threadIdx.x;
    if (t == 0) s_n = 0;
    __syncthreads();

    const int lane = t & 63;
    const int w    = t >> 6;         // 0..7
    const int B0   = bg * 128;

    // This thread's two beam dirs: sincos once, second = rotate by pi/4.
    const float a0 = (float)(B0 + lane) * ANG_STEP + th;
    const float rx0 = cosf(a0), ry0 = sinf(a0);
    const float rx1 = 0.70710678f * (rx0 - ry0);
    const float ry1 = 0.70710678f * (rx0 + ry0);

    {   // stage+cull: one segment per thread (all 512 threads)
        // Arc dirs from lane 0's beam (B0): d0 = rotate(-1 step), d1 = (-y, x).
        const float bx0 = __shfl(rx0, 0);
        const float by0 = __shfl(ry0, 0);
        const float d0x =  bx0 * C1 + by0 * S1;
        const float d0y = -bx0 * S1 + by0 * C1;
        const float d1x = -by0;
        const float d1y =  bx0;

        float4 v = seg[sc * CSEG2 + t];
        float ax = v.x - x1, ay = v.y - y1;     // P->A
        float bx = v.z - x1, by = v.w - y1;     // P->B
        float X0a = d0x * ay - d0y * ax;        // cross(d0, a)
        float Xa1 = ax * d1y - ay * d1x;        // cross(a, d1)
        float X0b = d0x * by - d0y * bx;        // cross(d0, b)
        float Xb1 = bx * d1y - by * d1x;        // cross(b, d1)
        float Xab = ax * by - ay * bx;          // cross(a, b)
        const float M = 0.25f;

        bool inA_a = (X0a >= -M) & (Xa1 >= -M);
        bool inA_b = (X0b >= -M) & (Xb1 >= -M);
        bool d0W, d1W;
        if (Xab >= 0.0f) {      // wedge CCW a -> b
            d0W = (X0a <=  M) & (X0b >= -M);
            d1W = (Xa1 >= -M) & (Xb1 <=  M);
        } else {                // wedge CCW b -> a
            d0W = (X0b <=  M) & (X0a >= -M);
            d1W = (Xb1 >= -M) & (Xa1 <=  M);
        }
        float la2 = ax * ax + ay * ay;
        float lb2 = bx * bx + by * by;
        bool degen = (Xab * Xab <= 4e-6f * la2 * lb2);  // P ~ on segment line

        if (inA_a | inA_b | d0W | d1W | degen) {
            int pos = atomicAdd(&s_n, 1);
            s4[pos] = make_float4(bx - ax, by - ay, -ax, -ay);  // {sx, sy, xd, yd}
        }
    }

    const float INF = __builtin_inff();
    __syncthreads();

    const int n = s_n;
    float u0 = INF, u1 = INF;
    #pragma unroll 4
    for (int i = w; i < n; i += 8) {
        float4 s = s4[i];                 // wave-uniform broadcast b128
        float na = s.x * s.w - s.y * s.z; // sx*yd - sy*xd (beam-independent)

        float rxs0 = s.y * rx0 - s.x * ry0;
        float nb0  = rx0 * s.w - ry0 * s.z;
        float r0   = __builtin_amdgcn_rcpf(rxs0);
        float ua0  = na  * r0;
        float ub0  = nb0 * r0;
        bool ok0 = (fabsf(rxs0) >= EPS_PAR) & (ub0 >= 0.0f) & (ub0 <= 1.0f) & (ua0 >= 0.0f);
        u0 = fminf(u0, ok0 ? ua0 : INF);

        float rxs1 = s.y * rx1 - s.x * ry1;
        float nb1  = rx1 * s.w - ry1 * s.z;
        float r1   = __builtin_amdgcn_rcpf(rxs1);
        float ua1  = na  * r1;
        float ub1  = nb1 * r1;
        bool ok1 = (fabsf(rxs1) >= EPS_PAR) & (ub1 >= 0.0f) & (ub1 <= 1.0f) & (ua1 >= 0.0f);
        u1 = fminf(u1, ok1 ? ua1 : INF);
    }

    s_red[w][lane]      = u0;
    s_red[w][lane + 64] = u1;
    __syncthreads();
    if (t < 128) {
        float m0 = fminf(fminf(s_red[0][t], s_red[1][t]),
                         fminf(s_red[2][t], s_red[3][t]));
        float m1 = fminf(fminf(s_red[4][t], s_red[5][t]),
                         fminf(s_red[6][t], s_red[7][t]));
        part[sc * (NB * L_OBS) + b * L_OBS + B0 + t] = fminf(m0, m1);
    }
}

// Parallel finalize: 64 blocks x 256 threads, 16 partial rows (4 per quarter).
__global__ __launch_bounds__(256) void finalize15_kernel(
    const float4* __restrict__ seg, const float* __restrict__ pose,
    const float* __restrict__ part, float* __restrict__ out) {
    __shared__ float s_red[4][64];

    const int t    = threadIdx.x;
    const int lane = t & 63;
    const int q    = t >> 6;
    const int gbeam = blockIdx.x * 64 + lane;   // 64 blocks cover 4096 beam-slots

    float u = INFINITY;
    #pragma unroll
    for (int j = 0; j < 4; ++j)
        u = fminf(u, part[(q * 4 + j) * (NB * L_OBS) + gbeam]);

    s_red[q][lane] = u;
    __syncthreads();
    if (t < 64) {
        const int gb   = blockIdx.x * 64 + t;
        const int b    = gb >> 9;
        const int beam = gb & (L_OBS - 1);
        const float x1 = pose[b * 3 + 0];
        const float y1 = pose[b * 3 + 1];
        const float th = pose[b * 3 + 2];
        const float ang = (float)beam * ANG_STEP + th;
        const float rx = cosf(ang), ry = sinf(ang);

        float m = fminf(fminf(s_red[0][t], s_red[1][t]),
                        fminf(s_red[2][t], s_red[3][t]));

        if (isinf(m)) {
            // No valid intersection: ref takes u_a[0] (argmin of all-inf -> idx 0).
            float4 s0 = seg[0];
            float sx = s0.z - s0.x, sy = s0.w - s0.y;
            float xd = x1 - s0.x,   yd = y1 - s0.y;
            float rxs   = sy * rx - sx * ry;
            float num_a = sx * yd - sy * xd;
            m = (fabsf(rxs) < EPS_PAR) ? 0.0f : (num_a / rxs);
        }

        float ix = x1 + rx * m;
        float iy = y1 + ry * m;
        float dx = ix - x1, dy = iy - y1;
        float c = cosf(th), s = sinf(th);
        out[gb * 2 + 0] = ix;
        out[gb * 2 + 1] = iy;
        const int off = NB * L_OBS * 2;
        out[off + gb * 2 + 0] =  dx * c + dy * s;   // R = [[c,-s],[s,c]], out = d @ R
        out[off + gb * 2 + 1] = -dx * s + dy * c;
    }
}

extern "C" void kernel_launch(void* const* d_in, const int* in_sizes, int n_in,
                              void* d_out, int out_size, void* d_ws, size_t ws_size,
                              hipStream_t stream) {
    const float4* seg  = (const float4*)d_in[0];   // (N,4) float32
    const float*  pose = (const float*)d_in[1];    // (B,3) float32
    float* out = (float*)d_out;
    float* part = (float*)d_ws;                    // [SC2][NB*L_OBS], 256 KB

    raycast15_kernel<<<NB * 4 * SC2, 512, 0, stream>>>(seg, pose, part);
    finalize15_kernel<<<64, 256, 0, stream>>>(seg, pose, part, out);
}

// Round 16
// 18.436 us; speedup vs baseline: 1.2743x; 1.0744x over previous
//
#include <hip/hip_runtime.h>
#include <math.h>

#define L_OBS   512
#define NSEG    8192
#define NB      8
#define EPS_PAR 1e-4f
#define ANG_STEP 0.012271846644580566f  // 2*pi / 512

// Rotation constants: 64*STEP = pi/4 exactly; 129*STEP = 1.58306822 rad.
#define C64   0.70710678118654752f
#define C129  (-0.0122715808f)
#define S129  (0.9999246959f)

#define SC2   32
#define CSEG2 (NSEG / SC2)               // 256 segs per block
#define PART2_FLOATS (SC2 * NB * L_OBS)  // 512 KB

// R13 skeleton (champion, 18.4us), one change: wave-aggregated LDS compaction
// (__ballot + popc prefix + 1 atomic per wave) replaces per-thread atomicAdd
// on the shared counter (same-address LDS atomics serialize ~6cyc each; 256
// per block -> lengthens the pre-barrier critical path every wave waits on).
// Proven in R14's stage; min over permuted set is order-independent -> exact.
__global__ __launch_bounds__(512) void raycast16_kernel(
    const float4* __restrict__ seg, const float* __restrict__ pose,
    float* __restrict__ part) {
    __shared__ float4 s4[CSEG2];     // compacted {sx, sy, xd, yd}
    __shared__ float  s_red[8][128];
    __shared__ int    s_n;

    const int gid = blockIdx.x;      // 1024 = 8b * 4bg * 32sc
    const int sc = gid & (SC2 - 1);
    const int bg = (gid >> 5) & 3;
    const int b  = gid >> 7;

    const float x1 = pose[b * 3 + 0];
    const float y1 = pose[b * 3 + 1];
    const float th = pose[b * 3 + 2];

    const int t = threadIdx.x;
    if (t == 0) s_n = 0;
    __syncthreads();

    const int lane = t & 63;
    const int w    = t >> 6;         // 0..7
    const int B0   = bg * 128;

    // This thread's two beam dirs: sincos once, second via rotation by pi/4.
    const int beam0 = B0 + lane;
    const float a0 = (float)beam0 * ANG_STEP + th;
    const float rx0 = cosf(a0), ry0 = sinf(a0);
    const float rx1 = C64 * (rx0 - ry0);
    const float ry1 = C64 * (rx0 + ry0);

    if (t < CSEG2) {                 // waves 0..3, all lanes active
        // Arc bounds with +-1 beam-step margin: d0 at (B0-1), d1 at (B0+128).
        const float aa = (float)(B0 - 1) * ANG_STEP + th;
        const float d0x = cosf(aa), d0y = sinf(aa);
        const float d1x = d0x * C129 - d0y * S129;
        const float d1y = d0x * S129 + d0y * C129;

        float4 v = seg[sc * CSEG2 + t];
        float ax = v.x - x1, ay = v.y - y1;     // dir P->A
        float bx = v.z - x1, by = v.w - y1;     // dir P->B
        float X0a = d0x * ay - d0y * ax;        // cross(d0, a)
        float Xa1 = ax * d1y - ay * d1x;        // cross(a, d1)
        float X0b = d0x * by - d0y * bx;        // cross(d0, b)
        float Xb1 = bx * d1y - by * d1x;        // cross(b, d1)
        float Xab = ax * by - ay * bx;          // cross(a, b)
        const float M = 0.25f;

        bool inA_a = (X0a >= -M) & (Xa1 >= -M);
        bool inA_b = (X0b >= -M) & (Xb1 >= -M);
        bool d0W, d1W;
        if (Xab >= 0.0f) {      // wedge runs CCW a -> b
            d0W = (X0a <=  M) & (X0b >= -M);
            d1W = (Xa1 >= -M) & (Xb1 <=  M);
        } else {                // wedge runs CCW b -> a
            d0W = (X0b <=  M) & (X0a >= -M);
            d1W = (Xb1 >= -M) & (Xa1 <=  M);
        }
        float la2 = ax * ax + ay * ay;
        float lb2 = bx * bx + by * by;
        bool degen = (Xab * Xab <= 4e-6f * la2 * lb2);  // P ~ on segment line
        bool keep = inA_a | inA_b | d0W | d1W | degen;

        // wave-aggregated compaction: 1 LDS atomic per wave
        unsigned long long mk = __ballot(keep);
        int pos = __popcll(mk & ((1ULL << lane) - 1));
        int basew = 0;
        if (lane == 0) basew = atomicAdd(&s_n, (int)__popcll(mk));
        basew = __shfl(basew, 0);
        if (keep)
            s4[basew + pos] = make_float4(bx - ax, by - ay, -ax, -ay);  // {sx,sy,xd,yd}
    }

    const float INF = __builtin_inff();
    __syncthreads();

    const int n = s_n;
    float u0 = INF, u1 = INF;
    #pragma unroll 4
    for (int i = w; i < n; i += 8) {
        float4 s = s4[i];                 // wave-uniform broadcast b128
        float na = s.x * s.w - s.y * s.z; // sx*yd - sy*xd (beam-independent)

        float rxs0 = s.y * rx0 - s.x * ry0;
        float nb0  = rx0 * s.w - ry0 * s.z;
        float r0   = __builtin_amdgcn_rcpf(rxs0);
        float ua0  = na  * r0;
        float ub0  = nb0 * r0;
        bool ok0 = (fabsf(rxs0) >= EPS_PAR) & (ub0 >= 0.0f) & (ub0 <= 1.0f) & (ua0 >= 0.0f);
        u0 = fminf(u0, ok0 ? ua0 : INF);

        float rxs1 = s.y * rx1 - s.x * ry1;
        float nb1  = rx1 * s.w - ry1 * s.z;
        float r1   = __builtin_amdgcn_rcpf(rxs1);
        float ua1  = na  * r1;
        float ub1  = nb1 * r1;
        bool ok1 = (fabsf(rxs1) >= EPS_PAR) & (ub1 >= 0.0f) & (ub1 <= 1.0f) & (ua1 >= 0.0f);
        u1 = fminf(u1, ok1 ? ua1 : INF);
    }

    s_red[w][lane]      = u0;
    s_red[w][lane + 64] = u1;
    __syncthreads();
    if (t < 128) {
        float m0 = fminf(fminf(s_red[0][t], s_red[1][t]),
                         fminf(s_red[2][t], s_red[3][t]));
        float m1 = fminf(fminf(s_red[4][t], s_red[5][t]),
                         fminf(s_red[6][t], s_red[7][t]));
        part[sc * (NB * L_OBS) + b * L_OBS + B0 + t] = fminf(m0, m1);
    }
}

// Parallel finalize (unchanged from R7/R13): 64 blocks x 256 threads.
__global__ __launch_bounds__(256) void finalize7_kernel(
    const float4* __restrict__ seg, const float* __restrict__ pose,
    const float* __restrict__ part, float* __restrict__ out) {
    __shared__ float s_red[4][64];

    const int t    = threadIdx.x;
    const int lane = t & 63;
    const int q    = t >> 6;
    const int gbeam = blockIdx.x * 64 + lane;   // 64 blocks cover 4096 beam-slots

    float u = INFINITY;
    #pragma unroll
    for (int j = 0; j < 8; ++j)
        u = fminf(u, part[(q * 8 + j) * (NB * L_OBS) + gbeam]);

    s_red[q][lane] = u;
    __syncthreads();
    if (t < 64) {
        const int gb   = blockIdx.x * 64 + t;
        const int b    = gb >> 9;
        const int beam = gb & (L_OBS - 1);
        const float x1 = pose[b * 3 + 0];
        const float y1 = pose[b * 3 + 1];
        const float th = pose[b * 3 + 2];
        const float ang = (float)beam * ANG_STEP + th;
        const float rx = cosf(ang), ry = sinf(ang);

        float m = fminf(fminf(s_red[0][t], s_red[1][t]),
                        fminf(s_red[2][t], s_red[3][t]));

        if (isinf(m)) {
            // No valid intersection: ref takes u_a[0] (argmin of all-inf -> idx 0).
            float4 s0 = seg[0];
            float sx = s0.z - s0.x, sy = s0.w - s0.y;
            float xd = x1 - s0.x,   yd = y1 - s0.y;
            float rxs   = sy * rx - sx * ry;
            float num_a = sx * yd - sy * xd;
            m = (fabsf(rxs) < EPS_PAR) ? 0.0f : (num_a / rxs);
        }

        float ix = x1 + rx * m;
        float iy = y1 + ry * m;
        float dx = ix - x1, dy = iy - y1;
        float c = cosf(th), s = sinf(th);
        out[gb * 2 + 0] = ix;
        out[gb * 2 + 1] = iy;
        const int off = NB * L_OBS * 2;
        out[off + gb * 2 + 0] =  dx * c + dy * s;   // R = [[c,-s],[s,c]], out = d @ R
        out[off + gb * 2 + 1] = -dx * s + dy * c;
    }
}

extern "C" void kernel_launch(void* const* d_in, const int* in_sizes, int n_in,
                              void* d_out, int out_size, void* d_ws, size_t ws_size,
                              hipStream_t stream) {
    const float4* seg  = (const float4*)d_in[0];   // (N,4) float32
    const float*  pose = (const float*)d_in[1];    // (B,3) float32
    float* out = (float*)d_out;
    float* part = (float*)d_ws;                    // [SC2][NB*L_OBS], 512 KB

    raycast16_kernel<<<1024, 512, 0, stream>>>(seg, pose, part);
    finalize7_kernel<<<64, 256, 0, stream>>>(seg, pose, part, out);
}